// Round 8
// baseline (551.611 us; speedup 1.0000x reference)
//
#include <hip/hip_runtime.h>

typedef __bf16 bf16_t;
typedef __bf16 bf16x8 __attribute__((ext_vector_type(8)));
typedef float f32x4 __attribute__((ext_vector_type(4)));
typedef float f32x2 __attribute__((ext_vector_type(2)));

#define N_NODES 50000
#define N_PAD   50048   // padded to multiple of 128 for 128-row GEMM tiles
#define N_EDGES 400000
#define D_IN    256
#define D_HID   512
#define D_OUT   128
#define N_LAYERS 4
#define ZROW    N_PAD                  // index of the always-zero table row (dummy gathers)
#define CSR_CAP (N_EDGES + 3 * N_NODES + 64)  // padded-slot capacity
#define PZ_FLOATS (3 * 512 * 512)      // P12,Q,P zero region

#define AS1 __attribute__((address_space(1)))
#define AS3 __attribute__((address_space(3)))

// ---------------- init + x conversion (merged: both linear, independent) ----------------

__global__ void init_convert(int* __restrict__ deg, int* __restrict__ cursor,
                             int* __restrict__ csr_src, float* __restrict__ dinv,
                             float* __restrict__ u0, float* __restrict__ u1,
                             float* __restrict__ u2, bf16_t* __restrict__ FA,
                             bf16_t* __restrict__ FB, float* __restrict__ Pz,
                             const float* __restrict__ x, bf16_t* __restrict__ xb,
                             int nconv) {
    int idx = blockIdx.x * blockDim.x + threadIdx.x;
    if (idx < CSR_CAP) csr_src[idx] = ZROW;
    if (idx < N_NODES) { deg[idx] = 0; cursor[idx] = 0; }
    if (idx < N_PAD - N_NODES) dinv[N_NODES + idx] = 0.0f;
    if (idx < N_PAD + 1 - N_NODES) {
        u0[N_NODES + idx] = 0.0f; u1[N_NODES + idx] = 0.0f; u2[N_NODES + idx] = 0.0f;
    }
    if (idx < 64) {   // ZROW of the 128-wide gather tables (128 bf16 = 64 dwords)
        ((unsigned*)(FA + (size_t)ZROW * D_OUT))[idx] = 0u;
        ((unsigned*)(FB + (size_t)ZROW * D_OUT))[idx] = 0u;
    }
    if (idx < PZ_FLOATS) Pz[idx] = 0.0f;
    const int c4 = idx * 4;
    if (c4 + 3 < nconv) {
        float4 v = *reinterpret_cast<const float4*>(x + c4);
        bf16_t o[4] = {(bf16_t)v.x, (bf16_t)v.y, (bf16_t)v.z, (bf16_t)v.w};
        *reinterpret_cast<uint2*>(xb + c4) = *reinterpret_cast<const uint2*>(o);
    }
}

// ---------------- transposes: W1 -> bf16 W1t; C2,C4,W2 -> fp32 transposed ----------------
// z: 0 = W1 (256x512 -> bf16), 1 = Wc[1] (C2, fp32T), 2 = Wc[3] (C4, fp32T), 3 = W2 (fp32T)

__global__ void transpose_all(const float* __restrict__ W1, const float* __restrict__ Wc,
                              const float* __restrict__ W2, bf16_t* __restrict__ W1t,
                              float* __restrict__ W2cT, float* __restrict__ W4cT,
                              float* __restrict__ W2T) {
    const float* in; int R, C; bf16_t* outb = nullptr; float* outf = nullptr;
    const int z = blockIdx.z;
    if (z == 0)      { in = W1; R = D_IN;  C = D_HID; outb = W1t; }
    else if (z == 1) { in = Wc + (size_t)1 * D_HID * D_HID; R = D_HID; C = D_HID; outf = W2cT; }
    else if (z == 2) { in = Wc + (size_t)3 * D_HID * D_HID; R = D_HID; C = D_HID; outf = W4cT; }
    else             { in = W2; R = D_HID; C = D_OUT; outf = W2T; }

    const int c0 = blockIdx.x * 32;
    const int r0 = blockIdx.y * 32;
    if (c0 >= C || r0 >= R) return;
    __shared__ float tile[32][33];
    for (int i = threadIdx.y; i < 32; i += 8)
        tile[i][threadIdx.x] = in[(size_t)(r0 + i) * C + c0 + threadIdx.x];
    __syncthreads();
    for (int i = threadIdx.y; i < 32; i += 8) {
        if (outb) outb[(size_t)(c0 + i) * R + r0 + threadIdx.x] = (bf16_t)tile[threadIdx.x][i];
        else      outf[(size_t)(c0 + i) * R + r0 + threadIdx.x] = tile[threadIdx.x][i];
    }
}

// ---------------- degree / padded CSR build ----------------

__global__ void count_deg(const int* __restrict__ dst, int* __restrict__ deg, int E) {
    int e = blockIdx.x * blockDim.x + threadIdx.x;
    if (e < E) atomicAdd(&deg[dst[e]], 1);
}

__global__ void scan_reduce(const int* __restrict__ deg, int* __restrict__ partial, int N) {
    __shared__ int red[256];
    int base = blockIdx.x * 1024;
    int s = 0;
    for (int i = threadIdx.x; i < 1024; i += 256) {
        int idx = base + i;
        s += (idx < N) ? ((deg[idx] + 3) & ~3) : 0;   // padded slots
    }
    red[threadIdx.x] = s;
    __syncthreads();
    for (int off = 128; off > 0; off >>= 1) {
        if (threadIdx.x < off) red[threadIdx.x] += red[threadIdx.x + off];
        __syncthreads();
    }
    if (threadIdx.x == 0) partial[blockIdx.x] = red[0];
}

__global__ void scan_partials(int* __restrict__ partial, int nb,
                              int* __restrict__ row_start, int N) {
    if (threadIdx.x == 0 && blockIdx.x == 0) {
        int acc = 0;
        for (int i = 0; i < nb; i++) { int v = partial[i]; partial[i] = acc; acc += v; }
        row_start[N] = acc;   // total padded slots
    }
}

__global__ void scan_chunks(const int* __restrict__ deg, const int* __restrict__ partial,
                            int* __restrict__ row_start, float* __restrict__ dinv,
                            float* __restrict__ u0, int N) {
    __shared__ int buf[2][1024];
    int t = threadIdx.x;
    int gid = blockIdx.x * 1024 + t;
    int d = (gid < N) ? deg[gid] : 0;
    int v = (gid < N) ? ((d + 3) & ~3) : 0;           // padded slots
    int cur = 0;
    buf[0][t] = v;
    __syncthreads();
    for (int off = 1; off < 1024; off <<= 1) {
        int nxt = cur ^ 1;
        int val = buf[cur][t];
        if (t >= off) val += buf[cur][t - off];
        buf[nxt][t] = val;
        cur = nxt;
        __syncthreads();
    }
    int incl = buf[cur][t];
    if (gid < N) {
        row_start[gid] = partial[blockIdx.x] + incl - v;  // exclusive
        float dv = rsqrtf((float)(d + 1));                // +1 self loop
        dinv[gid] = dv;
        u0[gid] = dv;                                     // u0 = dinv .* ones
    }
}

__global__ void fill_csr(const int* __restrict__ ei, int E,
                         const int* __restrict__ row_start,
                         int* __restrict__ cursor, int* __restrict__ csr_src) {
    int e = blockIdx.x * blockDim.x + threadIdx.x;
    if (e < E) {
        int s = ei[e];
        int d = ei[E + e];
        int pos = atomicAdd(&cursor[d], 1);
        csr_src[row_start[d] + pos] = s;
    }
}

// ---------------- GEMM: C = act(rowscale * (A @ BT^T) + bias) ----------------
// R0-proven structure: 128x128 tile, 4 waves, BK=64 single buffer,
// global_load_lds w=16, 4 blocks/CU. (R6 epilogue bug fixed in R7 — keep as-is.)

template <bool F32OUT, bool RELU>
__global__ __launch_bounds__(256, 4) void gemm_tile(
    const bf16_t* __restrict__ A, const bf16_t* __restrict__ BT,
    const float* __restrict__ bias, const float* __restrict__ rowscale,
    void* __restrict__ Cv, int M, int N, int K)
{
    __shared__ __align__(16) char smem[32768];  // sA 16KB + sB 16KB; epilogue reuse
    bf16_t* sA = (bf16_t*)smem;
    bf16_t* sB = (bf16_t*)(smem + 128 * 128);
    bf16_t* sC = (bf16_t*)smem;                 // 64 x 136 bf16 = 17.4 KB

    int bxi, byi;
    if (gridDim.x == 4) {
        const int bid = blockIdx.y * 4 + blockIdx.x;     // dispatch-linear id
        const int T0 = (int)(gridDim.y * 4) & ~31;
        if (bid < T0) { int q = bid >> 5, r = bid & 31; byi = q * 8 + (r & 7); bxi = r >> 3; }
        else          { int t = bid - T0; byi = (T0 >> 2) + (t >> 2); bxi = t & 3; }
    } else { bxi = blockIdx.x; byi = blockIdx.y; }

    const int tid  = threadIdx.x;
    const int lane = tid & 63;
    const int wave = tid >> 6;
    const int bn = bxi * 128;
    const int bm = byi * 128;
    const int wm = (wave & 1) * 64;
    const int wn = (wave >> 1) * 64;
    const int lm = lane & 15;
    const int lq = lane >> 4;

    // staging: each 1KB wave-load covers 8 rows x 8 chunks; lane (r8,c8)
    const int r8 = lane >> 3;
    const int c8 = lane & 7;
    const int ksw = (c8 ^ r8) * 8;              // swizzled k-offset (elements)

    f32x4 acc[4][4] = {};

    const int nkb = K >> 6;
    for (int kb = 0; kb < nkb; kb++) {
        const int k0 = kb * 64;
#pragma unroll
        for (int r = 0; r < 4; r++) {               // A: 16 groups of 8 rows
            const int g = r * 4 + wave;
            __builtin_amdgcn_global_load_lds(
                (const AS1 unsigned int*)(A + (size_t)(bm + g * 8 + r8) * K + k0 + ksw),
                (AS3 unsigned int*)((AS3 char*)(AS3 bf16_t*)sA + g * 1024),
                16, 0, 0);
        }
#pragma unroll
        for (int r = 0; r < 4; r++) {               // B: 16 groups of 8 rows
            const int g = r * 4 + wave;
            __builtin_amdgcn_global_load_lds(
                (const AS1 unsigned int*)(BT + (size_t)(bn + g * 8 + r8) * K + k0 + ksw),
                (AS3 unsigned int*)((AS3 char*)(AS3 bf16_t*)sB + g * 1024),
                16, 0, 0);
        }
        __syncthreads();

#pragma unroll
        for (int s = 0; s < 2; s++) {               // two K=32 steps per BK=64
            bf16x8 af[4], bfr[4];
#pragma unroll
            for (int mt = 0; mt < 4; mt++) {
                const int R = wm + mt * 16 + lm;
                const int g = s * 4 + lq;
                af[mt] = *reinterpret_cast<bf16x8*>(&sA[R * 64 + ((g ^ (R & 7)) * 8)]);
            }
#pragma unroll
            for (int nt = 0; nt < 4; nt++) {
                const int R = wn + nt * 16 + lm;
                const int g = s * 4 + lq;
                bfr[nt] = *reinterpret_cast<bf16x8*>(&sB[R * 64 + ((g ^ (R & 7)) * 8)]);
            }
#pragma unroll
            for (int mt = 0; mt < 4; mt++)
#pragma unroll
                for (int nt = 0; nt < 4; nt++)
                    acc[mt][nt] = __builtin_amdgcn_mfma_f32_16x16x32_bf16(af[mt], bfr[nt], acc[mt][nt], 0, 0, 0);
        }
        __syncthreads();
    }

    if (!F32OUT) {
        // coalesced epilogue: 2 passes of 64 rows through LDS; sC row stride 136 elems
        const size_t rowbytes = (size_t)N * 2;
#pragma unroll
        for (int p = 0; p < 2; p++) {
            if (p) __syncthreads();
            if ((wave & 1) == p) {
#pragma unroll
                for (int nt = 0; nt < 4; nt++) {
                    const int col = wn + nt * 16 + lm;
                    const float bv = bias ? bias[bn + col] : 0.0f;
#pragma unroll
                    for (int mt = 0; mt < 4; mt++) {
#pragma unroll
                        for (int r = 0; r < 4; r++) {
                            const int lrow = mt * 16 + lq * 4 + r;
                            float v = acc[mt][nt][r] + bv;
                            if (rowscale) v *= rowscale[bm + p * 64 + lrow];
                            if (RELU) v = fmaxf(v, 0.0f);
                            sC[lrow * 136 + col] = (bf16_t)v;
                        }
                    }
                }
            }
            __syncthreads();
            char* outbase = (char*)Cv + (size_t)(bm + p * 64) * rowbytes + (size_t)bn * 2;
#pragma unroll
            for (int j = 0; j < 4; j++) {
                const int idx = j * 4096 + tid * 16;
                const int row = idx >> 8;            // 256 data bytes per tile row
                const int colb = idx & 255;
                *reinterpret_cast<uint4*>(outbase + (size_t)row * rowbytes + colb) =
                    *reinterpret_cast<const uint4*>((char*)sC + (size_t)row * 272 + colb);
            }
        }
    } else {
        // scattered epilogue (fp32 out): C/D layout col=lane&15, row=lq*4+reg
#pragma unroll
        for (int nt = 0; nt < 4; nt++) {
            const int col = bn + wn + nt * 16 + lm;
            const float bv = bias ? bias[col] : 0.0f;
#pragma unroll
            for (int mt = 0; mt < 4; mt++) {
#pragma unroll
                for (int r = 0; r < 4; r++) {
                    const int row = bm + wm + mt * 16 + lq * 4 + r;
                    if (row < M) {
                        float v = acc[mt][nt][r] + bv;
                        if (rowscale) v *= rowscale[row];
                        if (RELU) v = fmaxf(v, 0.0f);
                        ((float*)Cv)[(size_t)row * N + col] = v;
                    }
                }
            }
        }
    }
}

// ---------------- mm3: small fp32-accurate GEMM via on-the-fly split-bf16 ----------------
// C[m][n] (+)= sum_k A[m][k]*BT[n][k], computed as Ah*Bh + Al*Bh + Ah*Bl (err ~2^-16).

__global__ __launch_bounds__(256) void mm3(
    const float* __restrict__ A0, const float* __restrict__ B0, float* __restrict__ C0,
    const float* __restrict__ A1, const float* __restrict__ B1, float* __restrict__ C1,
    bf16_t* __restrict__ Cb, int M, int N, int K, int kc, int outmode)
{
    int z = blockIdx.z;
    const float* A = A0; const float* BT = B0; float* C = C0;
    if (z >= kc) { A = A1; BT = B1; C = C1; z -= kc; }
    const int n0 = blockIdx.x * 64;
    const int m0 = blockIdx.y * 64;
    const int lane = threadIdx.x & 63;
    const int w    = threadIdx.x >> 6;
    const int lm = lane & 15, lq = lane >> 4;
    const int klen = K / kc;
    const int kbeg = z * klen;
    const int arow = m0 + w * 16 + lm;

    f32x4 acc[4] = {};
    for (int k = kbeg; k < kbeg + klen; k += 32) {
        const float* ap = A + (size_t)arow * K + k + lq * 8;
        float4 av0 = *reinterpret_cast<const float4*>(ap);
        float4 av1 = *reinterpret_cast<const float4*>(ap + 4);
        float av[8] = {av0.x, av0.y, av0.z, av0.w, av1.x, av1.y, av1.z, av1.w};
        bf16x8 ah, al;
#pragma unroll
        for (int j = 0; j < 8; j++) {
            bf16_t h = (bf16_t)av[j]; ah[j] = h; al[j] = (bf16_t)(av[j] - (float)h);
        }
#pragma unroll
        for (int nt = 0; nt < 4; nt++) {
            const float* bp = BT + (size_t)(n0 + nt * 16 + lm) * K + k + lq * 8;
            float4 bv0 = *reinterpret_cast<const float4*>(bp);
            float4 bv1 = *reinterpret_cast<const float4*>(bp + 4);
            float bv[8] = {bv0.x, bv0.y, bv0.z, bv0.w, bv1.x, bv1.y, bv1.z, bv1.w};
            bf16x8 bh, bl;
#pragma unroll
            for (int j = 0; j < 8; j++) {
                bf16_t h = (bf16_t)bv[j]; bh[j] = h; bl[j] = (bf16_t)(bv[j] - (float)h);
            }
            acc[nt] = __builtin_amdgcn_mfma_f32_16x16x32_bf16(ah, bh, acc[nt], 0, 0, 0);
            acc[nt] = __builtin_amdgcn_mfma_f32_16x16x32_bf16(al, bh, acc[nt], 0, 0, 0);
            acc[nt] = __builtin_amdgcn_mfma_f32_16x16x32_bf16(ah, bl, acc[nt], 0, 0, 0);
        }
    }
#pragma unroll
    for (int nt = 0; nt < 4; nt++) {
#pragma unroll
        for (int r = 0; r < 4; r++) {
            const int row = m0 + w * 16 + lq * 4 + r;
            const int col = n0 + nt * 16 + lm;
            if (outmode == 0) atomicAdd(&C[(size_t)row * N + col], acc[nt][r]);
            else              Cb[(size_t)row * N + col] = (bf16_t)acc[nt][r];
        }
    }
}

// ---------------- bias_chain: all 4 vstep launches in ONE single-block kernel ----------
// cvec rows = [bc0*C2C3C4*W2, bc1*C3C4*W2, bc2*C4*W2, bc3*W2 + b2]. V kept in LDS;
// chain steps separated by __syncthreads (replaces 4 dependent tiny dispatches).

__global__ __launch_bounds__(256) void bias_chain(
    const float* __restrict__ bc, const float* __restrict__ Wc,
    const float* __restrict__ W2, const float* __restrict__ b2,
    float* __restrict__ cvec)
{
    __shared__ float V[4][512];
    const int t = threadIdx.x;
#pragma unroll
    for (int r = 0; r < 4; r++) {
        V[r][t] = bc[r * 512 + t];
        V[r][t + 256] = bc[r * 512 + t + 256];
    }
    __syncthreads();
    for (int j = 0; j < 3; j++) {                 // multiply rows 0..j by Wc[j+1]
        const float* W = Wc + (size_t)(j + 1) * 512 * 512;
        float nv[3][2];
        for (int r = 0; r <= j; r++) {
            float a0 = 0.0f, a1 = 0.0f;
#pragma unroll 8
            for (int k = 0; k < 512; k++) {
                const float vk = V[r][k];
                a0 += vk * W[(size_t)k * 512 + t];
                a1 += vk * W[(size_t)k * 512 + t + 256];
            }
            nv[r][0] = a0; nv[r][1] = a1;
        }
        __syncthreads();
        for (int r = 0; r <= j; r++) { V[r][t] = nv[r][0]; V[r][t + 256] = nv[r][1]; }
        __syncthreads();
    }
    if (t < 128) {
#pragma unroll
        for (int r = 0; r < 4; r++) {
            float a = 0.0f;
#pragma unroll 8
            for (int k = 0; k < 512; k++) a += V[r][k] * W2[(size_t)k * 128 + t];
            if (r == 3) a += b2[t];
            cvec[r * 128 + t] = a;
        }
    }
}

// ---------------- s_agg: scalar aggregate s = dinv .* (u[self] + gather-sum) -------------

__global__ void s_agg(const float* __restrict__ uin, const float* __restrict__ dinv,
                      const int* __restrict__ row_start, const int* __restrict__ csr_src,
                      float* __restrict__ sout, float* __restrict__ uout, int N)
{
    int n = blockIdx.x * blockDim.x + threadIdx.x;
    if (n >= N) return;
    float a = uin[n];
    const int beg = row_start[n], end = row_start[n + 1];
    for (int i = beg; i < end; i++) a += uin[csr_src[i]];
    const float sv = dinv[n] * a;
    sout[n] = sv;
    uout[n] = dinv[n] * sv;
}

// ---------------- agg128: one hop of Ahat on a 128-wide table (grouped gathers) ----------
// R8 redesign: 4 lane-groups of 16; group g gathers slot i+g with 16B/lane ->
// one VMEM instruction moves 4 slots x 256B = 1KB (4x fewer instructions than
// R7's one-row-per-instruction, same cache lines). Cross-group feature sums
// combined by __shfl_xor butterfly (masks 16, 32). Group 0 holds the self term
// and does the stores.
// !FINAL: tout[n] = dinv[n]^2 * raw (prescaled for next hop), bf16.
// FINAL:  fout[n] = dinv[n]*raw + s3*c1 + s2*c2 + s1*c3 + c4  (fp32 output).

#define UNP4(accv, uvec) do {                                         \
    const unsigned* _w = reinterpret_cast<const unsigned*>(&(uvec));  \
    _Pragma("unroll")                                                 \
    for (int _j = 0; _j < 4; _j++) {                                  \
        (accv)[_j][0] += __uint_as_float(_w[_j] << 16);               \
        (accv)[_j][1] += __uint_as_float(_w[_j] & 0xffff0000u);       \
    }                                                                 \
} while (0)

template <bool FINAL>
__global__ __launch_bounds__(256) void agg128(
    const bf16_t* __restrict__ tin, const float* __restrict__ dinv,
    const int* __restrict__ row_start, const int* __restrict__ csr_src,
    bf16_t* __restrict__ tout, float* __restrict__ fout,
    const float* __restrict__ s1, const float* __restrict__ s2,
    const float* __restrict__ s3, const float* __restrict__ cvec, int N)
{
    const int n = blockIdx.x * 4 + (threadIdx.x >> 6);
    const int lane = threadIdx.x & 63;
    if (n >= N) return;
    const int g  = lane >> 4;          // slot group 0..3
    const int fl = lane & 15;          // 16B feature chunk within row
    const char* tb = (const char*)tin + fl * 16;

    f32x2 acc[4] = {};                 // this lane's 8 features (4 bf16-pairs)
    if (g == 0) {                      // self term, counted once via butterfly
        uint4 u = *reinterpret_cast<const uint4*>(tb + ((size_t)n << 8));
        UNP4(acc, u);
    }

    const int beg = row_start[n];
    const int cnt = row_start[n + 1] - beg;      // multiple of 4
    const int* ip = csr_src + beg + g;           // this group's slot stream

    int i = 0;
    for (; i + 16 <= cnt; i += 16) {             // 4 grouped gathers in flight
        const int sa = ip[i], sb = ip[i + 4], sc = ip[i + 8], sd = ip[i + 12];
        uint4 u0 = *reinterpret_cast<const uint4*>(tb + ((size_t)sa << 8));
        uint4 u1 = *reinterpret_cast<const uint4*>(tb + ((size_t)sb << 8));
        uint4 u2 = *reinterpret_cast<const uint4*>(tb + ((size_t)sc << 8));
        uint4 u3 = *reinterpret_cast<const uint4*>(tb + ((size_t)sd << 8));
        UNP4(acc, u0); UNP4(acc, u1); UNP4(acc, u2); UNP4(acc, u3);
    }
    if (i + 8 <= cnt) {
        const int sa = ip[i], sb = ip[i + 4];
        uint4 u0 = *reinterpret_cast<const uint4*>(tb + ((size_t)sa << 8));
        uint4 u1 = *reinterpret_cast<const uint4*>(tb + ((size_t)sb << 8));
        UNP4(acc, u0); UNP4(acc, u1);
        i += 8;
    }
    if (i < cnt) {
        const int sa = ip[i];
        uint4 u0 = *reinterpret_cast<const uint4*>(tb + ((size_t)sa << 8));
        UNP4(acc, u0);
    }

    // butterfly across the 4 groups: every lane ends with the full sum for its fl
#pragma unroll
    for (int j = 0; j < 4; j++) {
        acc[j][0] += __shfl_xor(acc[j][0], 16);
        acc[j][0] += __shfl_xor(acc[j][0], 32);
        acc[j][1] += __shfl_xor(acc[j][1], 16);
        acc[j][1] += __shfl_xor(acc[j][1], 32);
    }

    const float dn = dinv[n];
    if (!FINAL) {
        if (g == 0) {
            const float sc = dn * dn;
            bf16_t o[8];
#pragma unroll
            for (int j = 0; j < 4; j++) {
                o[2 * j]     = (bf16_t)(sc * acc[j][0]);
                o[2 * j + 1] = (bf16_t)(sc * acc[j][1]);
            }
            *reinterpret_cast<uint4*>((char*)tout + ((size_t)n << 8) + fl * 16) =
                *reinterpret_cast<const uint4*>(o);
        }
    } else {
        if (g == 0) {
            const int f = fl * 8;
            const float w3 = s3[n], w2 = s2[n], w1 = s1[n];
            float o[8];
#pragma unroll
            for (int j = 0; j < 4; j++) {
                o[2 * j]     = dn * acc[j][0];
                o[2 * j + 1] = dn * acc[j][1];
            }
#pragma unroll
            for (int j = 0; j < 8; j++)
                o[j] += w3 * cvec[f + j] + w2 * cvec[128 + f + j]
                      + w1 * cvec[256 + f + j] + cvec[384 + f + j];
            float* op = fout + (size_t)n * D_OUT + f;
            *reinterpret_cast<float4*>(op)     = make_float4(o[0], o[1], o[2], o[3]);
            *reinterpret_cast<float4*>(op + 4) = make_float4(o[4], o[5], o[6], o[7]);
        }
    }
}

// ---------------- orchestration ----------------
// Algebra (GCN layers are LINEAR — no activation between them):
//   out = Ahat^4 (h0 @ Wbig) + s3 (x) c1 + s2 (x) c2 + s1 (x) c3 + 1 (x) c4
//   Wbig = C1 C2 C3 C4 W2 (512x128), s_k = Ahat^k 1, c_k = bias chains.

extern "C" void kernel_launch(void* const* d_in, const int* in_sizes, int n_in,
                              void* d_out, int out_size, void* d_ws, size_t ws_size,
                              hipStream_t stream) {
    const int N = N_NODES, E = N_EDGES;
    const size_t DD = (size_t)D_HID * D_HID;

    const float* x  = (const float*)d_in[0];
    const int*   ei = (const int*)d_in[1];
    const float* W1 = (const float*)d_in[2];
    const float* b1 = (const float*)d_in[3];
    const float* Wc = (const float*)d_in[4];
    const float* bc = (const float*)d_in[5];
    const float* W2 = (const float*)d_in[6];
    const float* b2 = (const float*)d_in[7];
    float* out = (float*)d_out;

    char* ws = (char*)d_ws;
    size_t off = 0;
    auto alloc = [&](size_t bytes) -> void* {
        void* p = ws + off;
        off += (bytes + 255) & ~(size_t)255;
        return p;
    };
    int*    deg       = (int*)alloc((size_t)N * 4);
    int*    cursor    = (int*)alloc((size_t)N * 4);
    int*    row_start = (int*)alloc((size_t)(N + 1) * 4);
    int*    partial   = (int*)alloc(256 * 4);
    float*  dinv      = (float*)alloc((size_t)N_PAD * 4);
    float*  u0        = (float*)alloc((size_t)(N_PAD + 1) * 4);
    float*  u1        = (float*)alloc((size_t)(N_PAD + 1) * 4);
    float*  u2        = (float*)alloc((size_t)(N_PAD + 1) * 4);
    float*  s1        = (float*)alloc((size_t)N * 4);
    float*  s2        = (float*)alloc((size_t)N * 4);
    float*  s3        = (float*)alloc((size_t)N * 4);
    int*    csr_src   = (int*)alloc((size_t)CSR_CAP * 4);
    bf16_t* xb        = (bf16_t*)alloc((size_t)N_PAD * D_IN * 2);
    bf16_t* h0        = (bf16_t*)alloc((size_t)N_PAD * D_HID * 2);
    bf16_t* FA        = (bf16_t*)alloc((size_t)(N_PAD + 1) * D_OUT * 2);  // +1: ZROW
    bf16_t* FB        = (bf16_t*)alloc((size_t)(N_PAD + 1) * D_OUT * 2);  // +1: ZROW
    bf16_t* W1t       = (bf16_t*)alloc((size_t)D_HID * D_IN * 2);
    float*  W2cT      = (float*)alloc(DD * 4);
    float*  W4cT      = (float*)alloc(DD * 4);
    float*  W2T       = (float*)alloc((size_t)D_OUT * D_HID * 4);
    float*  Pz        = (float*)alloc(3 * DD * 4);     // P12 | Q | P (zeroed together)
    float*  P12 = Pz, *Q = Pz + DD, *P = Pz + 2 * DD;
    bf16_t* WbigT     = (bf16_t*)alloc((size_t)D_OUT * D_HID * 2);
    float*  cvec      = (float*)alloc(4 * 128 * 4);

    // init + x conversion (merged)
    {
        const int nconv = N * D_IN;
        const int nthreads = nconv / 4;          // 3.2M threads (covers all init ranges)
        init_convert<<<(nthreads + 255) / 256, 256, 0, stream>>>(
            deg, cursor, csr_src, dinv, u0, u1, u2, FA, FB, Pz, x, xb, nconv);
    }
    transpose_all<<<dim3(16, 16, 4), dim3(32, 8), 0, stream>>>(
        W1, Wc, W2, W1t, W2cT, W4cT, W2T);

    // padded CSR build
    count_deg<<<(E + 255) / 256, 256, 0, stream>>>(ei + E, deg, E);
    const int nch = (N + 1023) / 1024;
    scan_reduce<<<nch, 256, 0, stream>>>(deg, partial, N);
    scan_partials<<<1, 64, 0, stream>>>(partial, nch, row_start, N);
    scan_chunks<<<nch, 1024, 0, stream>>>(deg, partial, row_start, dinv, u0, N);
    fill_csr<<<(E + 255) / 256, 256, 0, stream>>>(ei, E, row_start, cursor, csr_src);

    // weight chain (fp32-accurate): P12 = C1@C2, Q = (C3@C4)^T, P = P12@(C3C4),
    // WbigT = (P@W2)^T as bf16 [128][512]
    mm3<<<dim3(8, 8, 8), 256, 0, stream>>>(
        Wc, W2cT, P12,                 // product A: C1 @ C2
        W4cT, Wc + 2 * DD, Q,          // product B: C4^T @ C3^T = (C3 C4)^T
        nullptr, 512, 512, 512, 4, 0);
    mm3<<<dim3(8, 8, 4), 256, 0, stream>>>(
        P12, Q, P, P12, Q, P, nullptr, 512, 512, 512, 4, 0);
    mm3<<<dim3(8, 2, 1), 256, 0, stream>>>(
        W2T, P, P, W2T, P, P, WbigT, 128, 512, 512, 1, 1);

    // bias chains (single block, replaces 4 vstep launches)
    bias_chain<<<1, 256, 0, stream>>>(bc, Wc, W2, b2, cvec);

    // s_k = Ahat^k 1
    s_agg<<<(N + 255) / 256, 256, 0, stream>>>(u0, dinv, row_start, csr_src, s1, u1, N);
    s_agg<<<(N + 255) / 256, 256, 0, stream>>>(u1, dinv, row_start, csr_src, s2, u2, N);
    s_agg<<<(N + 255) / 256, 256, 0, stream>>>(u2, dinv, row_start, csr_src, s3, u1, N);

    const dim3 blk(256);
    const int mg = N_PAD / 128;  // 391

    // dnn1: h0 = relu(x @ W1 + b1)
    gemm_tile<false, true><<<dim3(4, mg), blk, 0, stream>>>(
        xb, W1t, b1, nullptr, h0, N_PAD, D_HID, D_IN);

    // F = dinv .* (h0 @ Wbig)  (prescaled table t0, bf16 128-wide)
    gemm_tile<false, false><<<dim3(1, mg), blk, 0, stream>>>(
        h0, WbigT, nullptr, dinv, FA, N_PAD, D_OUT, D_HID);

    // four hops of Ahat (128-wide); last fuses the rank-4 bias correction + fp32 out
    const int ag = (N + 3) / 4;
    agg128<false><<<ag, blk, 0, stream>>>(FA, dinv, row_start, csr_src, FB, nullptr,
                                          nullptr, nullptr, nullptr, nullptr, N);
    agg128<false><<<ag, blk, 0, stream>>>(FB, dinv, row_start, csr_src, FA, nullptr,
                                          nullptr, nullptr, nullptr, nullptr, N);
    agg128<false><<<ag, blk, 0, stream>>>(FA, dinv, row_start, csr_src, FB, nullptr,
                                          nullptr, nullptr, nullptr, nullptr, N);
    agg128<true><<<ag, blk, 0, stream>>>(FB, dinv, row_start, csr_src, nullptr, out,
                                         s1, s2, s3, cvec, N);
}

// Round 9
// 538.395 us; speedup vs baseline: 1.0245x; 1.0245x over previous
//
#include <hip/hip_runtime.h>

typedef __bf16 bf16_t;
typedef __bf16 bf16x8 __attribute__((ext_vector_type(8)));
typedef float f32x4 __attribute__((ext_vector_type(4)));
typedef float f32x2 __attribute__((ext_vector_type(2)));

#define N_NODES 50000
#define N_PAD   50048   // padded to multiple of 128 for 128-row GEMM tiles
#define N_EDGES 400000
#define D_IN    256
#define D_HID   512
#define D_OUT   128
#define N_LAYERS 4
#define ZROW    N_PAD                  // index of the always-zero table row (dummy gathers)
#define CSR_CAP (N_EDGES + 3 * N_NODES + 64)  // padded-slot capacity
#define PZ_FLOATS (3 * 512 * 512)      // P12,Q,P zero region

#define AS1 __attribute__((address_space(1)))
#define AS3 __attribute__((address_space(3)))

// ---------------- init + x conversion (merged: both linear, independent) ----------------

__global__ void init_convert(int* __restrict__ deg, int* __restrict__ cursor,
                             int* __restrict__ csr_src, float* __restrict__ dinv,
                             float* __restrict__ u0, float* __restrict__ u1,
                             float* __restrict__ u2, bf16_t* __restrict__ FA,
                             bf16_t* __restrict__ FB, float* __restrict__ Pz,
                             const float* __restrict__ x, bf16_t* __restrict__ xb,
                             int nconv) {
    int idx = blockIdx.x * blockDim.x + threadIdx.x;
    if (idx < CSR_CAP) csr_src[idx] = ZROW;
    if (idx < N_NODES) { deg[idx] = 0; cursor[idx] = 0; }
    if (idx < N_PAD - N_NODES) dinv[N_NODES + idx] = 0.0f;
    if (idx < N_PAD + 1 - N_NODES) {
        u0[N_NODES + idx] = 0.0f; u1[N_NODES + idx] = 0.0f; u2[N_NODES + idx] = 0.0f;
    }
    if (idx < 64) {   // ZROW of the 128-wide gather tables (128 bf16 = 64 dwords)
        ((unsigned*)(FA + (size_t)ZROW * D_OUT))[idx] = 0u;
        ((unsigned*)(FB + (size_t)ZROW * D_OUT))[idx] = 0u;
    }
    if (idx < PZ_FLOATS) Pz[idx] = 0.0f;
    const int c4 = idx * 4;
    if (c4 + 3 < nconv) {
        float4 v = *reinterpret_cast<const float4*>(x + c4);
        bf16_t o[4] = {(bf16_t)v.x, (bf16_t)v.y, (bf16_t)v.z, (bf16_t)v.w};
        *reinterpret_cast<uint2*>(xb + c4) = *reinterpret_cast<const uint2*>(o);
    }
}

// ---------------- transposes: W1 -> bf16 W1t; C2,C4,W2 -> fp32 transposed ----------------
// z: 0 = W1 (256x512 -> bf16), 1 = Wc[1] (C2, fp32T), 2 = Wc[3] (C4, fp32T), 3 = W2 (fp32T)

__global__ void transpose_all(const float* __restrict__ W1, const float* __restrict__ Wc,
                              const float* __restrict__ W2, bf16_t* __restrict__ W1t,
                              float* __restrict__ W2cT, float* __restrict__ W4cT,
                              float* __restrict__ W2T) {
    const float* in; int R, C; bf16_t* outb = nullptr; float* outf = nullptr;
    const int z = blockIdx.z;
    if (z == 0)      { in = W1; R = D_IN;  C = D_HID; outb = W1t; }
    else if (z == 1) { in = Wc + (size_t)1 * D_HID * D_HID; R = D_HID; C = D_HID; outf = W2cT; }
    else if (z == 2) { in = Wc + (size_t)3 * D_HID * D_HID; R = D_HID; C = D_HID; outf = W4cT; }
    else             { in = W2; R = D_HID; C = D_OUT; outf = W2T; }

    const int c0 = blockIdx.x * 32;
    const int r0 = blockIdx.y * 32;
    if (c0 >= C || r0 >= R) return;
    __shared__ float tile[32][33];
    for (int i = threadIdx.y; i < 32; i += 8)
        tile[i][threadIdx.x] = in[(size_t)(r0 + i) * C + c0 + threadIdx.x];
    __syncthreads();
    for (int i = threadIdx.y; i < 32; i += 8) {
        if (outb) outb[(size_t)(c0 + i) * R + r0 + threadIdx.x] = (bf16_t)tile[threadIdx.x][i];
        else      outf[(size_t)(c0 + i) * R + r0 + threadIdx.x] = tile[threadIdx.x][i];
    }
}

// ---------------- degree / padded CSR build ----------------

__global__ void count_deg(const int* __restrict__ dst, int* __restrict__ deg, int E) {
    int e = blockIdx.x * blockDim.x + threadIdx.x;
    if (e < E) atomicAdd(&deg[dst[e]], 1);
}

__global__ void scan_reduce(const int* __restrict__ deg, int* __restrict__ partial, int N) {
    __shared__ int red[256];
    int base = blockIdx.x * 1024;
    int s = 0;
    for (int i = threadIdx.x; i < 1024; i += 256) {
        int idx = base + i;
        s += (idx < N) ? ((deg[idx] + 3) & ~3) : 0;   // padded slots
    }
    red[threadIdx.x] = s;
    __syncthreads();
    for (int off = 128; off > 0; off >>= 1) {
        if (threadIdx.x < off) red[threadIdx.x] += red[threadIdx.x + off];
        __syncthreads();
    }
    if (threadIdx.x == 0) partial[blockIdx.x] = red[0];
}

__global__ void scan_partials(int* __restrict__ partial, int nb,
                              int* __restrict__ row_start, int N) {
    if (threadIdx.x == 0 && blockIdx.x == 0) {
        int acc = 0;
        for (int i = 0; i < nb; i++) { int v = partial[i]; partial[i] = acc; acc += v; }
        row_start[N] = acc;   // total padded slots
    }
}

__global__ void scan_chunks(const int* __restrict__ deg, const int* __restrict__ partial,
                            int* __restrict__ row_start, float* __restrict__ dinv,
                            float* __restrict__ u0, int N) {
    __shared__ int buf[2][1024];
    int t = threadIdx.x;
    int gid = blockIdx.x * 1024 + t;
    int d = (gid < N) ? deg[gid] : 0;
    int v = (gid < N) ? ((d + 3) & ~3) : 0;           // padded slots
    int cur = 0;
    buf[0][t] = v;
    __syncthreads();
    for (int off = 1; off < 1024; off <<= 1) {
        int nxt = cur ^ 1;
        int val = buf[cur][t];
        if (t >= off) val += buf[cur][t - off];
        buf[nxt][t] = val;
        cur = nxt;
        __syncthreads();
    }
    int incl = buf[cur][t];
    if (gid < N) {
        row_start[gid] = partial[blockIdx.x] + incl - v;  // exclusive
        float dv = rsqrtf((float)(d + 1));                // +1 self loop
        dinv[gid] = dv;
        u0[gid] = dv;                                     // u0 = dinv .* ones
    }
}

__global__ void fill_csr(const int* __restrict__ ei, int E,
                         const int* __restrict__ row_start,
                         int* __restrict__ cursor, int* __restrict__ csr_src) {
    int e = blockIdx.x * blockDim.x + threadIdx.x;
    if (e < E) {
        int s = ei[e];
        int d = ei[E + e];
        int pos = atomicAdd(&cursor[d], 1);
        csr_src[row_start[d] + pos] = s;
    }
}

// ---------------- GEMM: C = act(rowscale * (A @ BT^T) + bias) ----------------
// R0-proven structure: 128x128 tile, 4 waves, BK=64 single buffer,
// global_load_lds w=16, 4 blocks/CU. (R6 epilogue bug fixed in R7 — keep as-is.)

template <bool F32OUT, bool RELU>
__global__ __launch_bounds__(256, 4) void gemm_tile(
    const bf16_t* __restrict__ A, const bf16_t* __restrict__ BT,
    const float* __restrict__ bias, const float* __restrict__ rowscale,
    void* __restrict__ Cv, int M, int N, int K)
{
    __shared__ __align__(16) char smem[32768];  // sA 16KB + sB 16KB; epilogue reuse
    bf16_t* sA = (bf16_t*)smem;
    bf16_t* sB = (bf16_t*)(smem + 128 * 128);
    bf16_t* sC = (bf16_t*)smem;                 // 64 x 136 bf16 = 17.4 KB

    int bxi, byi;
    if (gridDim.x == 4) {
        const int bid = blockIdx.y * 4 + blockIdx.x;     // dispatch-linear id
        const int T0 = (int)(gridDim.y * 4) & ~31;
        if (bid < T0) { int q = bid >> 5, r = bid & 31; byi = q * 8 + (r & 7); bxi = r >> 3; }
        else          { int t = bid - T0; byi = (T0 >> 2) + (t >> 2); bxi = t & 3; }
    } else { bxi = blockIdx.x; byi = blockIdx.y; }

    const int tid  = threadIdx.x;
    const int lane = tid & 63;
    const int wave = tid >> 6;
    const int bn = bxi * 128;
    const int bm = byi * 128;
    const int wm = (wave & 1) * 64;
    const int wn = (wave >> 1) * 64;
    const int lm = lane & 15;
    const int lq = lane >> 4;

    // staging: each 1KB wave-load covers 8 rows x 8 chunks; lane (r8,c8)
    const int r8 = lane >> 3;
    const int c8 = lane & 7;
    const int ksw = (c8 ^ r8) * 8;              // swizzled k-offset (elements)

    f32x4 acc[4][4] = {};

    const int nkb = K >> 6;
    for (int kb = 0; kb < nkb; kb++) {
        const int k0 = kb * 64;
#pragma unroll
        for (int r = 0; r < 4; r++) {               // A: 16 groups of 8 rows
            const int g = r * 4 + wave;
            __builtin_amdgcn_global_load_lds(
                (const AS1 unsigned int*)(A + (size_t)(bm + g * 8 + r8) * K + k0 + ksw),
                (AS3 unsigned int*)((AS3 char*)(AS3 bf16_t*)sA + g * 1024),
                16, 0, 0);
        }
#pragma unroll
        for (int r = 0; r < 4; r++) {               // B: 16 groups of 8 rows
            const int g = r * 4 + wave;
            __builtin_amdgcn_global_load_lds(
                (const AS1 unsigned int*)(BT + (size_t)(bn + g * 8 + r8) * K + k0 + ksw),
                (AS3 unsigned int*)((AS3 char*)(AS3 bf16_t*)sB + g * 1024),
                16, 0, 0);
        }
        __syncthreads();

#pragma unroll
        for (int s = 0; s < 2; s++) {               // two K=32 steps per BK=64
            bf16x8 af[4], bfr[4];
#pragma unroll
            for (int mt = 0; mt < 4; mt++) {
                const int R = wm + mt * 16 + lm;
                const int g = s * 4 + lq;
                af[mt] = *reinterpret_cast<bf16x8*>(&sA[R * 64 + ((g ^ (R & 7)) * 8)]);
            }
#pragma unroll
            for (int nt = 0; nt < 4; nt++) {
                const int R = wn + nt * 16 + lm;
                const int g = s * 4 + lq;
                bfr[nt] = *reinterpret_cast<bf16x8*>(&sB[R * 64 + ((g ^ (R & 7)) * 8)]);
            }
#pragma unroll
            for (int mt = 0; mt < 4; mt++)
#pragma unroll
                for (int nt = 0; nt < 4; nt++)
                    acc[mt][nt] = __builtin_amdgcn_mfma_f32_16x16x32_bf16(af[mt], bfr[nt], acc[mt][nt], 0, 0, 0);
        }
        __syncthreads();
    }

    if (!F32OUT) {
        // coalesced epilogue: 2 passes of 64 rows through LDS; sC row stride 136 elems
        const size_t rowbytes = (size_t)N * 2;
#pragma unroll
        for (int p = 0; p < 2; p++) {
            if (p) __syncthreads();
            if ((wave & 1) == p) {
#pragma unroll
                for (int nt = 0; nt < 4; nt++) {
                    const int col = wn + nt * 16 + lm;
                    const float bv = bias ? bias[bn + col] : 0.0f;
#pragma unroll
                    for (int mt = 0; mt < 4; mt++) {
#pragma unroll
                        for (int r = 0; r < 4; r++) {
                            const int lrow = mt * 16 + lq * 4 + r;
                            float v = acc[mt][nt][r] + bv;
                            if (rowscale) v *= rowscale[bm + p * 64 + lrow];
                            if (RELU) v = fmaxf(v, 0.0f);
                            sC[lrow * 136 + col] = (bf16_t)v;
                        }
                    }
                }
            }
            __syncthreads();
            char* outbase = (char*)Cv + (size_t)(bm + p * 64) * rowbytes + (size_t)bn * 2;
#pragma unroll
            for (int j = 0; j < 4; j++) {
                const int idx = j * 4096 + tid * 16;
                const int row = idx >> 8;            // 256 data bytes per tile row
                const int colb = idx & 255;
                *reinterpret_cast<uint4*>(outbase + (size_t)row * rowbytes + colb) =
                    *reinterpret_cast<const uint4*>((char*)sC + (size_t)row * 272 + colb);
            }
        }
    } else {
        // scattered epilogue (fp32 out): C/D layout col=lane&15, row=lq*4+reg
#pragma unroll
        for (int nt = 0; nt < 4; nt++) {
            const int col = bn + wn + nt * 16 + lm;
            const float bv = bias ? bias[col] : 0.0f;
#pragma unroll
            for (int mt = 0; mt < 4; mt++) {
#pragma unroll
                for (int r = 0; r < 4; r++) {
                    const int row = bm + wm + mt * 16 + lq * 4 + r;
                    if (row < M) {
                        float v = acc[mt][nt][r] + bv;
                        if (rowscale) v *= rowscale[row];
                        if (RELU) v = fmaxf(v, 0.0f);
                        ((float*)Cv)[(size_t)row * N + col] = v;
                    }
                }
            }
        }
    }
}

// ---------------- mm3: small fp32-accurate GEMM via on-the-fly split-bf16 ----------------
// C[m][n] (+)= sum_k A[m][k]*BT[n][k], computed as Ah*Bh + Al*Bh + Ah*Bl (err ~2^-16).

__global__ __launch_bounds__(256) void mm3(
    const float* __restrict__ A0, const float* __restrict__ B0, float* __restrict__ C0,
    const float* __restrict__ A1, const float* __restrict__ B1, float* __restrict__ C1,
    bf16_t* __restrict__ Cb, int M, int N, int K, int kc, int outmode)
{
    int z = blockIdx.z;
    const float* A = A0; const float* BT = B0; float* C = C0;
    if (z >= kc) { A = A1; BT = B1; C = C1; z -= kc; }
    const int n0 = blockIdx.x * 64;
    const int m0 = blockIdx.y * 64;
    const int lane = threadIdx.x & 63;
    const int w    = threadIdx.x >> 6;
    const int lm = lane & 15, lq = lane >> 4;
    const int klen = K / kc;
    const int kbeg = z * klen;
    const int arow = m0 + w * 16 + lm;

    f32x4 acc[4] = {};
    for (int k = kbeg; k < kbeg + klen; k += 32) {
        const float* ap = A + (size_t)arow * K + k + lq * 8;
        float4 av0 = *reinterpret_cast<const float4*>(ap);
        float4 av1 = *reinterpret_cast<const float4*>(ap + 4);
        float av[8] = {av0.x, av0.y, av0.z, av0.w, av1.x, av1.y, av1.z, av1.w};
        bf16x8 ah, al;
#pragma unroll
        for (int j = 0; j < 8; j++) {
            bf16_t h = (bf16_t)av[j]; ah[j] = h; al[j] = (bf16_t)(av[j] - (float)h);
        }
#pragma unroll
        for (int nt = 0; nt < 4; nt++) {
            const float* bp = BT + (size_t)(n0 + nt * 16 + lm) * K + k + lq * 8;
            float4 bv0 = *reinterpret_cast<const float4*>(bp);
            float4 bv1 = *reinterpret_cast<const float4*>(bp + 4);
            float bv[8] = {bv0.x, bv0.y, bv0.z, bv0.w, bv1.x, bv1.y, bv1.z, bv1.w};
            bf16x8 bh, bl;
#pragma unroll
            for (int j = 0; j < 8; j++) {
                bf16_t h = (bf16_t)bv[j]; bh[j] = h; bl[j] = (bf16_t)(bv[j] - (float)h);
            }
            acc[nt] = __builtin_amdgcn_mfma_f32_16x16x32_bf16(ah, bh, acc[nt], 0, 0, 0);
            acc[nt] = __builtin_amdgcn_mfma_f32_16x16x32_bf16(al, bh, acc[nt], 0, 0, 0);
            acc[nt] = __builtin_amdgcn_mfma_f32_16x16x32_bf16(ah, bl, acc[nt], 0, 0, 0);
        }
    }
#pragma unroll
    for (int nt = 0; nt < 4; nt++) {
#pragma unroll
        for (int r = 0; r < 4; r++) {
            const int row = m0 + w * 16 + lq * 4 + r;
            const int col = n0 + nt * 16 + lm;
            if (outmode == 0) atomicAdd(&C[(size_t)row * N + col], acc[nt][r]);
            else              Cb[(size_t)row * N + col] = (bf16_t)acc[nt][r];
        }
    }
}

// ---------------- vstep: bias-chain propagation (R7-proven parallel form) ----------
// Vout[r][c] = (r < rcnt) ? sum_k Vin[r][k]*W[k][c] (+ addb[c] if r==3) : Vin[r][c]
// Vin rows stride 512. Grid = Ncols/64, block 256 (4 rows x 64 cols).
// R8 post-mortem: single-block bias_chain was 161 us (1 CU, VALUBusy 0.03%) —
// Guideline-1 violation. This 8-block form is ~8-10 us/step.

__global__ void vstep(const float* __restrict__ Vin, const float* __restrict__ W,
                      float* __restrict__ Vout, int rcnt, int Ncols,
                      const float* __restrict__ addb) {
    const int r = threadIdx.x >> 6;
    const int c = blockIdx.x * 64 + (threadIdx.x & 63);
    if (r < rcnt) {
        float acc = 0.0f;
        for (int k = 0; k < D_HID; k++) acc += Vin[r * D_HID + k] * W[(size_t)k * Ncols + c];
        if (addb && r == 3) acc += addb[c];
        Vout[r * Ncols + c] = acc;
    } else {
        Vout[r * Ncols + c] = Vin[r * D_HID + c];
    }
}

// ---------------- s_agg: scalar aggregate s = dinv .* (u[self] + gather-sum) -------------

__global__ void s_agg(const float* __restrict__ uin, const float* __restrict__ dinv,
                      const int* __restrict__ row_start, const int* __restrict__ csr_src,
                      float* __restrict__ sout, float* __restrict__ uout, int N)
{
    int n = blockIdx.x * blockDim.x + threadIdx.x;
    if (n >= N) return;
    float a = uin[n];
    const int beg = row_start[n], end = row_start[n + 1];
    for (int i = beg; i < end; i++) a += uin[csr_src[i]];
    const float sv = dinv[n] * a;
    sout[n] = sv;
    uout[n] = dinv[n] * sv;
}

// ---------------- agg128: one hop of Ahat on a 128-wide table (grouped gathers) ----------
// R8-proven: 4 lane-groups of 16; group g gathers slot i+g with 16B/lane ->
// one VMEM instruction moves 4 slots x 256B = 1KB. Cross-group feature sums
// combined by __shfl_xor butterfly (masks 16, 32). Group 0 holds the self term
// and does the stores.
// !FINAL: tout[n] = dinv[n]^2 * raw (prescaled for next hop), bf16.
// FINAL:  fout[n] = dinv[n]*raw + s3*c1 + s2*c2 + s1*c3 + c4  (fp32 output).

#define UNP4(accv, uvec) do {                                         \
    const unsigned* _w = reinterpret_cast<const unsigned*>(&(uvec));  \
    _Pragma("unroll")                                                 \
    for (int _j = 0; _j < 4; _j++) {                                  \
        (accv)[_j][0] += __uint_as_float(_w[_j] << 16);               \
        (accv)[_j][1] += __uint_as_float(_w[_j] & 0xffff0000u);       \
    }                                                                 \
} while (0)

template <bool FINAL>
__global__ __launch_bounds__(256) void agg128(
    const bf16_t* __restrict__ tin, const float* __restrict__ dinv,
    const int* __restrict__ row_start, const int* __restrict__ csr_src,
    bf16_t* __restrict__ tout, float* __restrict__ fout,
    const float* __restrict__ s1, const float* __restrict__ s2,
    const float* __restrict__ s3, const float* __restrict__ cvec, int N)
{
    const int n = blockIdx.x * 4 + (threadIdx.x >> 6);
    const int lane = threadIdx.x & 63;
    if (n >= N) return;
    const int g  = lane >> 4;          // slot group 0..3
    const int fl = lane & 15;          // 16B feature chunk within row
    const char* tb = (const char*)tin + fl * 16;

    f32x2 acc[4] = {};                 // this lane's 8 features (4 bf16-pairs)
    if (g == 0) {                      // self term, counted once via butterfly
        uint4 u = *reinterpret_cast<const uint4*>(tb + ((size_t)n << 8));
        UNP4(acc, u);
    }

    const int beg = row_start[n];
    const int cnt = row_start[n + 1] - beg;      // multiple of 4
    const int* ip = csr_src + beg + g;           // this group's slot stream

    int i = 0;
    for (; i + 16 <= cnt; i += 16) {             // 4 grouped gathers in flight
        const int sa = ip[i], sb = ip[i + 4], sc = ip[i + 8], sd = ip[i + 12];
        uint4 u0 = *reinterpret_cast<const uint4*>(tb + ((size_t)sa << 8));
        uint4 u1 = *reinterpret_cast<const uint4*>(tb + ((size_t)sb << 8));
        uint4 u2 = *reinterpret_cast<const uint4*>(tb + ((size_t)sc << 8));
        uint4 u3 = *reinterpret_cast<const uint4*>(tb + ((size_t)sd << 8));
        UNP4(acc, u0); UNP4(acc, u1); UNP4(acc, u2); UNP4(acc, u3);
    }
    if (i + 8 <= cnt) {
        const int sa = ip[i], sb = ip[i + 4];
        uint4 u0 = *reinterpret_cast<const uint4*>(tb + ((size_t)sa << 8));
        uint4 u1 = *reinterpret_cast<const uint4*>(tb + ((size_t)sb << 8));
        UNP4(acc, u0); UNP4(acc, u1);
        i += 8;
    }
    if (i < cnt) {
        const int sa = ip[i];
        uint4 u0 = *reinterpret_cast<const uint4*>(tb + ((size_t)sa << 8));
        UNP4(acc, u0);
    }

    // butterfly across the 4 groups: every lane ends with the full sum for its fl
#pragma unroll
    for (int j = 0; j < 4; j++) {
        acc[j][0] += __shfl_xor(acc[j][0], 16);
        acc[j][0] += __shfl_xor(acc[j][0], 32);
        acc[j][1] += __shfl_xor(acc[j][1], 16);
        acc[j][1] += __shfl_xor(acc[j][1], 32);
    }

    const float dn = dinv[n];
    if (!FINAL) {
        if (g == 0) {
            const float sc = dn * dn;
            bf16_t o[8];
#pragma unroll
            for (int j = 0; j < 4; j++) {
                o[2 * j]     = (bf16_t)(sc * acc[j][0]);
                o[2 * j + 1] = (bf16_t)(sc * acc[j][1]);
            }
            *reinterpret_cast<uint4*>((char*)tout + ((size_t)n << 8) + fl * 16) =
                *reinterpret_cast<const uint4*>(o);
        }
    } else {
        if (g == 0) {
            const int f = fl * 8;
            const float w3 = s3[n], w2 = s2[n], w1 = s1[n];
            float o[8];
#pragma unroll
            for (int j = 0; j < 4; j++) {
                o[2 * j]     = dn * acc[j][0];
                o[2 * j + 1] = dn * acc[j][1];
            }
#pragma unroll
            for (int j = 0; j < 8; j++)
                o[j] += w3 * cvec[f + j] + w2 * cvec[128 + f + j]
                      + w1 * cvec[256 + f + j] + cvec[384 + f + j];
            float* op = fout + (size_t)n * D_OUT + f;
            *reinterpret_cast<float4*>(op)     = make_float4(o[0], o[1], o[2], o[3]);
            *reinterpret_cast<float4*>(op + 4) = make_float4(o[4], o[5], o[6], o[7]);
        }
    }
}

// ---------------- orchestration ----------------
// Algebra (GCN layers are LINEAR — no activation between them):
//   out = Ahat^4 (h0 @ Wbig) + s3 (x) c1 + s2 (x) c2 + s1 (x) c3 + 1 (x) c4
//   Wbig = C1 C2 C3 C4 W2 (512x128), s_k = Ahat^k 1, c_k = bias chains.

extern "C" void kernel_launch(void* const* d_in, const int* in_sizes, int n_in,
                              void* d_out, int out_size, void* d_ws, size_t ws_size,
                              hipStream_t stream) {
    const int N = N_NODES, E = N_EDGES;
    const size_t DD = (size_t)D_HID * D_HID;

    const float* x  = (const float*)d_in[0];
    const int*   ei = (const int*)d_in[1];
    const float* W1 = (const float*)d_in[2];
    const float* b1 = (const float*)d_in[3];
    const float* Wc = (const float*)d_in[4];
    const float* bc = (const float*)d_in[5];
    const float* W2 = (const float*)d_in[6];
    const float* b2 = (const float*)d_in[7];
    float* out = (float*)d_out;

    char* ws = (char*)d_ws;
    size_t off = 0;
    auto alloc = [&](size_t bytes) -> void* {
        void* p = ws + off;
        off += (bytes + 255) & ~(size_t)255;
        return p;
    };
    int*    deg       = (int*)alloc((size_t)N * 4);
    int*    cursor    = (int*)alloc((size_t)N * 4);
    int*    row_start = (int*)alloc((size_t)(N + 1) * 4);
    int*    partial   = (int*)alloc(256 * 4);
    float*  dinv      = (float*)alloc((size_t)N_PAD * 4);
    float*  u0        = (float*)alloc((size_t)(N_PAD + 1) * 4);
    float*  u1        = (float*)alloc((size_t)(N_PAD + 1) * 4);
    float*  u2        = (float*)alloc((size_t)(N_PAD + 1) * 4);
    float*  s1        = (float*)alloc((size_t)N * 4);
    float*  s2        = (float*)alloc((size_t)N * 4);
    float*  s3        = (float*)alloc((size_t)N * 4);
    int*    csr_src   = (int*)alloc((size_t)CSR_CAP * 4);
    bf16_t* xb        = (bf16_t*)alloc((size_t)N_PAD * D_IN * 2);
    bf16_t* h0        = (bf16_t*)alloc((size_t)N_PAD * D_HID * 2);
    bf16_t* FA        = (bf16_t*)alloc((size_t)(N_PAD + 1) * D_OUT * 2);  // +1: ZROW
    bf16_t* FB        = (bf16_t*)alloc((size_t)(N_PAD + 1) * D_OUT * 2);  // +1: ZROW
    bf16_t* W1t       = (bf16_t*)alloc((size_t)D_HID * D_IN * 2);
    float*  W2cT      = (float*)alloc(DD * 4);
    float*  W4cT      = (float*)alloc(DD * 4);
    float*  W2T       = (float*)alloc((size_t)D_OUT * D_HID * 4);
    float*  Pz        = (float*)alloc(3 * DD * 4);     // P12 | Q | P (zeroed together)
    float*  P12 = Pz, *Q = Pz + DD, *P = Pz + 2 * DD;
    bf16_t* WbigT     = (bf16_t*)alloc((size_t)D_OUT * D_HID * 2);
    float*  V0        = (float*)alloc(4 * 512 * 4);
    float*  V1        = (float*)alloc(4 * 512 * 4);
    float*  cvec      = (float*)alloc(4 * 128 * 4);

    // init + x conversion (merged)
    {
        const int nconv = N * D_IN;
        const int nthreads = nconv / 4;          // 3.2M threads (covers all init ranges)
        init_convert<<<(nthreads + 255) / 256, 256, 0, stream>>>(
            deg, cursor, csr_src, dinv, u0, u1, u2, FA, FB, Pz, x, xb, nconv);
    }
    transpose_all<<<dim3(16, 16, 4), dim3(32, 8), 0, stream>>>(
        W1, Wc, W2, W1t, W2cT, W4cT, W2T);

    // padded CSR build
    count_deg<<<(E + 255) / 256, 256, 0, stream>>>(ei + E, deg, E);
    const int nch = (N + 1023) / 1024;
    scan_reduce<<<nch, 256, 0, stream>>>(deg, partial, N);
    scan_partials<<<1, 64, 0, stream>>>(partial, nch, row_start, N);
    scan_chunks<<<nch, 1024, 0, stream>>>(deg, partial, row_start, dinv, u0, N);
    fill_csr<<<(E + 255) / 256, 256, 0, stream>>>(ei, E, row_start, cursor, csr_src);

    // weight chain (fp32-accurate): P12 = C1@C2, Q = (C3@C4)^T, P = P12@(C3C4),
    // WbigT = (P@W2)^T as bf16 [128][512]
    mm3<<<dim3(8, 8, 8), 256, 0, stream>>>(
        Wc, W2cT, P12,                 // product A: C1 @ C2
        W4cT, Wc + 2 * DD, Q,          // product B: C4^T @ C3^T = (C3 C4)^T
        nullptr, 512, 512, 512, 4, 0);
    mm3<<<dim3(8, 8, 4), 256, 0, stream>>>(
        P12, Q, P, P12, Q, P, nullptr, 512, 512, 512, 4, 0);
    mm3<<<dim3(8, 2, 1), 256, 0, stream>>>(
        W2T, P, P, W2T, P, P, WbigT, 128, 512, 512, 1, 1);

    // bias chains: cvec rows = [b1*C2C3C4W2, b2*C3C4W2, b3*C4W2, b4*W2 + b2out]
    vstep<<<8, 256, 0, stream>>>(bc, Wc + DD,     V0,   1, 512, nullptr);
    vstep<<<8, 256, 0, stream>>>(V0, Wc + 2 * DD, V1,   2, 512, nullptr);
    vstep<<<8, 256, 0, stream>>>(V1, Wc + 3 * DD, V0,   3, 512, nullptr);
    vstep<<<2, 256, 0, stream>>>(V0, W2,          cvec, 4, 128, b2);

    // s_k = Ahat^k 1
    s_agg<<<(N + 255) / 256, 256, 0, stream>>>(u0, dinv, row_start, csr_src, s1, u1, N);
    s_agg<<<(N + 255) / 256, 256, 0, stream>>>(u1, dinv, row_start, csr_src, s2, u2, N);
    s_agg<<<(N + 255) / 256, 256, 0, stream>>>(u2, dinv, row_start, csr_src, s3, u1, N);

    const dim3 blk(256);
    const int mg = N_PAD / 128;  // 391

    // dnn1: h0 = relu(x @ W1 + b1)
    gemm_tile<false, true><<<dim3(4, mg), blk, 0, stream>>>(
        xb, W1t, b1, nullptr, h0, N_PAD, D_HID, D_IN);

    // F = dinv .* (h0 @ Wbig)  (prescaled table t0, bf16 128-wide)
    gemm_tile<false, false><<<dim3(1, mg), blk, 0, stream>>>(
        h0, WbigT, nullptr, dinv, FA, N_PAD, D_OUT, D_HID);

    // four hops of Ahat (128-wide); last fuses the rank-4 bias correction + fp32 out
    const int ag = (N + 3) / 4;
    agg128<false><<<ag, blk, 0, stream>>>(FA, dinv, row_start, csr_src, FB, nullptr,
                                          nullptr, nullptr, nullptr, nullptr, N);
    agg128<false><<<ag, blk, 0, stream>>>(FB, dinv, row_start, csr_src, FA, nullptr,
                                          nullptr, nullptr, nullptr, nullptr, N);
    agg128<false><<<ag, blk, 0, stream>>>(FA, dinv, row_start, csr_src, FB, nullptr,
                                          nullptr, nullptr, nullptr, nullptr, N);
    agg128<true><<<ag, blk, 0, stream>>>(FB, dinv, row_start, csr_src, nullptr, out,
                                         s1, s2, s3, cvec, N);
}

// Round 10
// 427.127 us; speedup vs baseline: 1.2914x; 1.2605x over previous
//
#include <hip/hip_runtime.h>

typedef __bf16 bf16_t;
typedef __bf16 bf16x8 __attribute__((ext_vector_type(8)));
typedef float f32x4 __attribute__((ext_vector_type(4)));
typedef float f32x2 __attribute__((ext_vector_type(2)));

#define N_NODES 50000
#define N_PAD   50048   // padded to multiple of 128 for 128-row GEMM tiles
#define N_EDGES 400000
#define D_IN    256
#define D_HID   512
#define D_OUT   128
#define N_LAYERS 4
#define ZROW    N_PAD                  // index of the always-zero table row (dummy gathers)
#define CSR_CAP (N_EDGES + 3 * N_NODES + 64)  // padded-slot capacity
#define TZ_FLOATS (3 * 128 * 512)      // T3t,T2t,T1t zero region (atomicAdd targets)

#define AS1 __attribute__((address_space(1)))
#define AS3 __attribute__((address_space(3)))

// ---------------- init + x conversion (merged: both linear, independent) ----------------

__global__ void init_convert(int* __restrict__ deg, int* __restrict__ cursor,
                             int* __restrict__ csr_src, float* __restrict__ dinv,
                             float* __restrict__ u0, float* __restrict__ u1,
                             float* __restrict__ u2, bf16_t* __restrict__ FA,
                             bf16_t* __restrict__ FB, float* __restrict__ Tz,
                             const float* __restrict__ x, bf16_t* __restrict__ xb,
                             int nconv) {
    int idx = blockIdx.x * blockDim.x + threadIdx.x;
    if (idx < CSR_CAP) csr_src[idx] = ZROW;
    if (idx < N_NODES) { deg[idx] = 0; cursor[idx] = 0; }
    if (idx < N_PAD - N_NODES) dinv[N_NODES + idx] = 0.0f;
    if (idx < N_PAD + 1 - N_NODES) {
        u0[N_NODES + idx] = 0.0f; u1[N_NODES + idx] = 0.0f; u2[N_NODES + idx] = 0.0f;
    }
    if (idx < 64) {   // ZROW of the 128-wide gather tables (128 bf16 = 64 dwords)
        ((unsigned*)(FA + (size_t)ZROW * D_OUT))[idx] = 0u;
        ((unsigned*)(FB + (size_t)ZROW * D_OUT))[idx] = 0u;
    }
    if (idx < TZ_FLOATS) Tz[idx] = 0.0f;
    const int c4 = idx * 4;
    if (c4 + 3 < nconv) {
        float4 v = *reinterpret_cast<const float4*>(x + c4);
        bf16_t o[4] = {(bf16_t)v.x, (bf16_t)v.y, (bf16_t)v.z, (bf16_t)v.w};
        *reinterpret_cast<uint2*>(xb + c4) = *reinterpret_cast<const uint2*>(o);
    }
}

// ---------------- transposes: W1 -> bf16 W1t; W2 -> fp32 W2T ----------------
// z: 0 = W1 (256x512 -> bf16), 1 = W2 (512x128 -> fp32 W2T [128][512])

__global__ void transpose_all(const float* __restrict__ W1, const float* __restrict__ W2,
                              bf16_t* __restrict__ W1t, float* __restrict__ W2T) {
    const float* in; int R, C; bf16_t* outb = nullptr; float* outf = nullptr;
    const int z = blockIdx.z;
    if (z == 0) { in = W1; R = D_IN;  C = D_HID; outb = W1t; }
    else        { in = W2; R = D_HID; C = D_OUT; outf = W2T; }

    const int c0 = blockIdx.x * 32;
    const int r0 = blockIdx.y * 32;
    if (c0 >= C || r0 >= R) return;
    __shared__ float tile[32][33];
    for (int i = threadIdx.y; i < 32; i += 8)
        tile[i][threadIdx.x] = in[(size_t)(r0 + i) * C + c0 + threadIdx.x];
    __syncthreads();
    for (int i = threadIdx.y; i < 32; i += 8) {
        if (outb) outb[(size_t)(c0 + i) * R + r0 + threadIdx.x] = (bf16_t)tile[threadIdx.x][i];
        else      outf[(size_t)(c0 + i) * R + r0 + threadIdx.x] = tile[threadIdx.x][i];
    }
}

// ---------------- degree / padded CSR build ----------------

__global__ void count_deg(const int* __restrict__ dst, int* __restrict__ deg, int E) {
    int e = blockIdx.x * blockDim.x + threadIdx.x;
    if (e < E) atomicAdd(&deg[dst[e]], 1);
}

__global__ void scan_reduce(const int* __restrict__ deg, int* __restrict__ partial, int N) {
    __shared__ int red[256];
    int base = blockIdx.x * 1024;
    int s = 0;
    for (int i = threadIdx.x; i < 1024; i += 256) {
        int idx = base + i;
        s += (idx < N) ? ((deg[idx] + 3) & ~3) : 0;   // padded slots
    }
    red[threadIdx.x] = s;
    __syncthreads();
    for (int off = 128; off > 0; off >>= 1) {
        if (threadIdx.x < off) red[threadIdx.x] += red[threadIdx.x + off];
        __syncthreads();
    }
    if (threadIdx.x == 0) partial[blockIdx.x] = red[0];
}

__global__ void scan_partials(int* __restrict__ partial, int nb,
                              int* __restrict__ row_start, int N) {
    if (threadIdx.x == 0 && blockIdx.x == 0) {
        int acc = 0;
        for (int i = 0; i < nb; i++) { int v = partial[i]; partial[i] = acc; acc += v; }
        row_start[N] = acc;   // total padded slots
    }
}

__global__ void scan_chunks(const int* __restrict__ deg, const int* __restrict__ partial,
                            int* __restrict__ row_start, float* __restrict__ dinv,
                            float* __restrict__ u0, int N) {
    __shared__ int buf[2][1024];
    int t = threadIdx.x;
    int gid = blockIdx.x * 1024 + t;
    int d = (gid < N) ? deg[gid] : 0;
    int v = (gid < N) ? ((d + 3) & ~3) : 0;           // padded slots
    int cur = 0;
    buf[0][t] = v;
    __syncthreads();
    for (int off = 1; off < 1024; off <<= 1) {
        int nxt = cur ^ 1;
        int val = buf[cur][t];
        if (t >= off) val += buf[cur][t - off];
        buf[nxt][t] = val;
        cur = nxt;
        __syncthreads();
    }
    int incl = buf[cur][t];
    if (gid < N) {
        row_start[gid] = partial[blockIdx.x] + incl - v;  // exclusive
        float dv = rsqrtf((float)(d + 1));                // +1 self loop
        dinv[gid] = dv;
        u0[gid] = dv;                                     // u0 = dinv .* ones
    }
}

__global__ void fill_csr(const int* __restrict__ ei, int E,
                         const int* __restrict__ row_start,
                         int* __restrict__ cursor, int* __restrict__ csr_src) {
    int e = blockIdx.x * blockDim.x + threadIdx.x;
    if (e < E) {
        int s = ei[e];
        int d = ei[E + e];
        int pos = atomicAdd(&cursor[d], 1);
        csr_src[row_start[d] + pos] = s;
    }
}

// ---------------- GEMM: C = act(rowscale * (A @ BT^T) + bias) ----------------
// R0-proven structure: 128x128 tile, 4 waves, BK=64 single buffer,
// global_load_lds w=16, 4 blocks/CU.

template <bool F32OUT, bool RELU>
__global__ __launch_bounds__(256, 4) void gemm_tile(
    const bf16_t* __restrict__ A, const bf16_t* __restrict__ BT,
    const float* __restrict__ bias, const float* __restrict__ rowscale,
    void* __restrict__ Cv, int M, int N, int K)
{
    __shared__ __align__(16) char smem[32768];  // sA 16KB + sB 16KB; epilogue reuse
    bf16_t* sA = (bf16_t*)smem;
    bf16_t* sB = (bf16_t*)(smem + 128 * 128);
    bf16_t* sC = (bf16_t*)smem;                 // 64 x 136 bf16 = 17.4 KB

    int bxi, byi;
    if (gridDim.x == 4) {
        const int bid = blockIdx.y * 4 + blockIdx.x;     // dispatch-linear id
        const int T0 = (int)(gridDim.y * 4) & ~31;
        if (bid < T0) { int q = bid >> 5, r = bid & 31; byi = q * 8 + (r & 7); bxi = r >> 3; }
        else          { int t = bid - T0; byi = (T0 >> 2) + (t >> 2); bxi = t & 3; }
    } else { bxi = blockIdx.x; byi = blockIdx.y; }

    const int tid  = threadIdx.x;
    const int lane = tid & 63;
    const int wave = tid >> 6;
    const int bn = bxi * 128;
    const int bm = byi * 128;
    const int wm = (wave & 1) * 64;
    const int wn = (wave >> 1) * 64;
    const int lm = lane & 15;
    const int lq = lane >> 4;

    // staging: each 1KB wave-load covers 8 rows x 8 chunks; lane (r8,c8)
    const int r8 = lane >> 3;
    const int c8 = lane & 7;
    const int ksw = (c8 ^ r8) * 8;              // swizzled k-offset (elements)

    f32x4 acc[4][4] = {};

    const int nkb = K >> 6;
    for (int kb = 0; kb < nkb; kb++) {
        const int k0 = kb * 64;
#pragma unroll
        for (int r = 0; r < 4; r++) {               // A: 16 groups of 8 rows
            const int g = r * 4 + wave;
            __builtin_amdgcn_global_load_lds(
                (const AS1 unsigned int*)(A + (size_t)(bm + g * 8 + r8) * K + k0 + ksw),
                (AS3 unsigned int*)((AS3 char*)(AS3 bf16_t*)sA + g * 1024),
                16, 0, 0);
        }
#pragma unroll
        for (int r = 0; r < 4; r++) {               // B: 16 groups of 8 rows
            const int g = r * 4 + wave;
            __builtin_amdgcn_global_load_lds(
                (const AS1 unsigned int*)(BT + (size_t)(bn + g * 8 + r8) * K + k0 + ksw),
                (AS3 unsigned int*)((AS3 char*)(AS3 bf16_t*)sB + g * 1024),
                16, 0, 0);
        }
        __syncthreads();

#pragma unroll
        for (int s = 0; s < 2; s++) {               // two K=32 steps per BK=64
            bf16x8 af[4], bfr[4];
#pragma unroll
            for (int mt = 0; mt < 4; mt++) {
                const int R = wm + mt * 16 + lm;
                const int g = s * 4 + lq;
                af[mt] = *reinterpret_cast<bf16x8*>(&sA[R * 64 + ((g ^ (R & 7)) * 8)]);
            }
#pragma unroll
            for (int nt = 0; nt < 4; nt++) {
                const int R = wn + nt * 16 + lm;
                const int g = s * 4 + lq;
                bfr[nt] = *reinterpret_cast<bf16x8*>(&sB[R * 64 + ((g ^ (R & 7)) * 8)]);
            }
#pragma unroll
            for (int mt = 0; mt < 4; mt++)
#pragma unroll
                for (int nt = 0; nt < 4; nt++)
                    acc[mt][nt] = __builtin_amdgcn_mfma_f32_16x16x32_bf16(af[mt], bfr[nt], acc[mt][nt], 0, 0, 0);
        }
        __syncthreads();
    }

    if (!F32OUT) {
        // coalesced epilogue: 2 passes of 64 rows through LDS; sC row stride 136 elems
        const size_t rowbytes = (size_t)N * 2;
#pragma unroll
        for (int p = 0; p < 2; p++) {
            if (p) __syncthreads();
            if ((wave & 1) == p) {
#pragma unroll
                for (int nt = 0; nt < 4; nt++) {
                    const int col = wn + nt * 16 + lm;
                    const float bv = bias ? bias[bn + col] : 0.0f;
#pragma unroll
                    for (int mt = 0; mt < 4; mt++) {
#pragma unroll
                        for (int r = 0; r < 4; r++) {
                            const int lrow = mt * 16 + lq * 4 + r;
                            float v = acc[mt][nt][r] + bv;
                            if (rowscale) v *= rowscale[bm + p * 64 + lrow];
                            if (RELU) v = fmaxf(v, 0.0f);
                            sC[lrow * 136 + col] = (bf16_t)v;
                        }
                    }
                }
            }
            __syncthreads();
            char* outbase = (char*)Cv + (size_t)(bm + p * 64) * rowbytes + (size_t)bn * 2;
#pragma unroll
            for (int j = 0; j < 4; j++) {
                const int idx = j * 4096 + tid * 16;
                const int row = idx >> 8;            // 256 data bytes per tile row
                const int colb = idx & 255;
                *reinterpret_cast<uint4*>(outbase + (size_t)row * rowbytes + colb) =
                    *reinterpret_cast<const uint4*>((char*)sC + (size_t)row * 272 + colb);
            }
        }
    } else {
        // scattered epilogue (fp32 out): C/D layout col=lane&15, row=lq*4+reg
#pragma unroll
        for (int nt = 0; nt < 4; nt++) {
            const int col = bn + wn + nt * 16 + lm;
            const float bv = bias ? bias[col] : 0.0f;
#pragma unroll
            for (int mt = 0; mt < 4; mt++) {
#pragma unroll
                for (int r = 0; r < 4; r++) {
                    const int row = bm + wm + mt * 16 + lq * 4 + r;
                    if (row < M) {
                        float v = acc[mt][nt][r] + bv;
                        if (rowscale) v *= rowscale[row];
                        if (RELU) v = fmaxf(v, 0.0f);
                        ((float*)Cv)[(size_t)row * N + col] = v;
                    }
                }
            }
        }
    }
}

// ---------------- mm3: small fp32-accurate GEMM via on-the-fly split-bf16 ----------------
// C[m][n] (+)= sum_k A[m][k]*BT[n][k], computed as Ah*Bh + Al*Bh + Ah*Bl (err ~2^-16).
// R10: used for the right-associated T-chain (M=128): each step is
// mm3(A=T_{r+1}t [128][512], BT=C_r [512][512] row-major as given).
// outmode 0: atomicAdd fp32 into C (pre-zeroed). outmode 1 (kc==1): bf16 store to Cb.

__global__ __launch_bounds__(256) void mm3(
    const float* __restrict__ A, const float* __restrict__ BT, float* __restrict__ C,
    bf16_t* __restrict__ Cb, int M, int N, int K, int kc, int outmode)
{
    const int z = blockIdx.z;
    const int n0 = blockIdx.x * 64;
    const int m0 = blockIdx.y * 64;
    const int lane = threadIdx.x & 63;
    const int w    = threadIdx.x >> 6;
    const int lm = lane & 15, lq = lane >> 4;
    const int klen = K / kc;
    const int kbeg = z * klen;
    const int arow = m0 + w * 16 + lm;

    f32x4 acc[4] = {};
    for (int k = kbeg; k < kbeg + klen; k += 32) {
        const float* ap = A + (size_t)arow * K + k + lq * 8;
        float4 av0 = *reinterpret_cast<const float4*>(ap);
        float4 av1 = *reinterpret_cast<const float4*>(ap + 4);
        float av[8] = {av0.x, av0.y, av0.z, av0.w, av1.x, av1.y, av1.z, av1.w};
        bf16x8 ah, al;
#pragma unroll
        for (int j = 0; j < 8; j++) {
            bf16_t h = (bf16_t)av[j]; ah[j] = h; al[j] = (bf16_t)(av[j] - (float)h);
        }
#pragma unroll
        for (int nt = 0; nt < 4; nt++) {
            const float* bp = BT + (size_t)(n0 + nt * 16 + lm) * K + k + lq * 8;
            float4 bv0 = *reinterpret_cast<const float4*>(bp);
            float4 bv1 = *reinterpret_cast<const float4*>(bp + 4);
            float bv[8] = {bv0.x, bv0.y, bv0.z, bv0.w, bv1.x, bv1.y, bv1.z, bv1.w};
            bf16x8 bh, bl;
#pragma unroll
            for (int j = 0; j < 8; j++) {
                bf16_t h = (bf16_t)bv[j]; bh[j] = h; bl[j] = (bf16_t)(bv[j] - (float)h);
            }
            acc[nt] = __builtin_amdgcn_mfma_f32_16x16x32_bf16(ah, bh, acc[nt], 0, 0, 0);
            acc[nt] = __builtin_amdgcn_mfma_f32_16x16x32_bf16(al, bh, acc[nt], 0, 0, 0);
            acc[nt] = __builtin_amdgcn_mfma_f32_16x16x32_bf16(ah, bl, acc[nt], 0, 0, 0);
        }
    }
#pragma unroll
    for (int nt = 0; nt < 4; nt++) {
#pragma unroll
        for (int r = 0; r < 4; r++) {
            const int row = m0 + w * 16 + lq * 4 + r;
            const int col = n0 + nt * 16 + lm;
            if (outmode == 0) atomicAdd(&C[(size_t)row * N + col], acc[nt][r]);
            else              Cb[(size_t)row * N + col] = (bf16_t)acc[nt][r];
        }
    }
}

// ---------------- bias_mv: c_r = T_rt . bc_{r-1} (+ b2 for r=4) ----------------
// Replaces the 4-launch vstep chain: cvec[(r)*128+n] = sum_k T[n][k]*bc[r][k].
// Grid 2 x 256 threads; each thread one 512-dot via float4 loads (T L2-resident).

__global__ void bias_mv(const float* __restrict__ T1t, const float* __restrict__ T2t,
                        const float* __restrict__ T3t, const float* __restrict__ W2T,
                        const float* __restrict__ bc, const float* __restrict__ b2,
                        float* __restrict__ cvec) {
    const int id = blockIdx.x * 256 + threadIdx.x;
    if (id >= 512) return;
    const int r = id >> 7;
    const int n = id & 127;
    const float* T = (r == 0) ? T1t : (r == 1) ? T2t : (r == 2) ? T3t : W2T;
    const float* b = bc + r * 512;
    float a = 0.0f;
#pragma unroll 4
    for (int k = 0; k < 512; k += 4) {
        float4 tv = *reinterpret_cast<const float4*>(T + (size_t)n * 512 + k);
        float4 bv = *reinterpret_cast<const float4*>(b + k);
        a += tv.x * bv.x + tv.y * bv.y + tv.z * bv.z + tv.w * bv.w;
    }
    if (r == 3) a += b2[n];
    cvec[r * 128 + n] = a;
}

// ---------------- s_agg: scalar aggregate s = dinv .* (u[self] + gather-sum) -------------

__global__ void s_agg(const float* __restrict__ uin, const float* __restrict__ dinv,
                      const int* __restrict__ row_start, const int* __restrict__ csr_src,
                      float* __restrict__ sout, float* __restrict__ uout, int N)
{
    int n = blockIdx.x * blockDim.x + threadIdx.x;
    if (n >= N) return;
    float a = uin[n];
    const int beg = row_start[n], end = row_start[n + 1];
    for (int i = beg; i < end; i++) a += uin[csr_src[i]];
    const float sv = dinv[n] * a;
    sout[n] = sv;
    uout[n] = dinv[n] * sv;
}

// ---------------- agg128: one hop of Ahat on a 128-wide table (grouped gathers) ----------
// 4 lane-groups of 16; group g gathers slot i+g with 16B/lane -> one VMEM
// instruction moves 4 slots x 256B = 1KB. Cross-group sums via __shfl_xor
// butterfly (masks 16, 32). Group 0 holds the self term and stores.
// !FINAL: tout[n] = dinv[n]^2 * raw (prescaled for next hop), bf16.
// FINAL:  fout[n] = dinv[n]*raw + s3*c1 + s2*c2 + s1*c3 + c4  (fp32 output).

#define UNP4(accv, uvec) do {                                         \
    const unsigned* _w = reinterpret_cast<const unsigned*>(&(uvec));  \
    _Pragma("unroll")                                                 \
    for (int _j = 0; _j < 4; _j++) {                                  \
        (accv)[_j][0] += __uint_as_float(_w[_j] << 16);               \
        (accv)[_j][1] += __uint_as_float(_w[_j] & 0xffff0000u);       \
    }                                                                 \
} while (0)

template <bool FINAL>
__global__ __launch_bounds__(256) void agg128(
    const bf16_t* __restrict__ tin, const float* __restrict__ dinv,
    const int* __restrict__ row_start, const int* __restrict__ csr_src,
    bf16_t* __restrict__ tout, float* __restrict__ fout,
    const float* __restrict__ s1, const float* __restrict__ s2,
    const float* __restrict__ s3, const float* __restrict__ cvec, int N)
{
    const int n = blockIdx.x * 4 + (threadIdx.x >> 6);
    const int lane = threadIdx.x & 63;
    if (n >= N) return;
    const int g  = lane >> 4;          // slot group 0..3
    const int fl = lane & 15;          // 16B feature chunk within row
    const char* tb = (const char*)tin + fl * 16;

    f32x2 acc[4] = {};                 // this lane's 8 features (4 bf16-pairs)
    if (g == 0) {                      // self term, counted once via butterfly
        uint4 u = *reinterpret_cast<const uint4*>(tb + ((size_t)n << 8));
        UNP4(acc, u);
    }

    const int beg = row_start[n];
    const int cnt = row_start[n + 1] - beg;      // multiple of 4
    const int* ip = csr_src + beg + g;           // this group's slot stream

    int i = 0;
    for (; i + 16 <= cnt; i += 16) {             // 4 grouped gathers in flight
        const int sa = ip[i], sb = ip[i + 4], sc = ip[i + 8], sd = ip[i + 12];
        uint4 u0 = *reinterpret_cast<const uint4*>(tb + ((size_t)sa << 8));
        uint4 u1 = *reinterpret_cast<const uint4*>(tb + ((size_t)sb << 8));
        uint4 u2 = *reinterpret_cast<const uint4*>(tb + ((size_t)sc << 8));
        uint4 u3 = *reinterpret_cast<const uint4*>(tb + ((size_t)sd << 8));
        UNP4(acc, u0); UNP4(acc, u1); UNP4(acc, u2); UNP4(acc, u3);
    }
    if (i + 8 <= cnt) {
        const int sa = ip[i], sb = ip[i + 4];
        uint4 u0 = *reinterpret_cast<const uint4*>(tb + ((size_t)sa << 8));
        uint4 u1 = *reinterpret_cast<const uint4*>(tb + ((size_t)sb << 8));
        UNP4(acc, u0); UNP4(acc, u1);
        i += 8;
    }
    if (i < cnt) {
        const int sa = ip[i];
        uint4 u0 = *reinterpret_cast<const uint4*>(tb + ((size_t)sa << 8));
        UNP4(acc, u0);
    }

    // butterfly across the 4 groups: every lane ends with the full sum for its fl
#pragma unroll
    for (int j = 0; j < 4; j++) {
        acc[j][0] += __shfl_xor(acc[j][0], 16);
        acc[j][0] += __shfl_xor(acc[j][0], 32);
        acc[j][1] += __shfl_xor(acc[j][1], 16);
        acc[j][1] += __shfl_xor(acc[j][1], 32);
    }

    const float dn = dinv[n];
    if (!FINAL) {
        if (g == 0) {
            const float sc = dn * dn;
            bf16_t o[8];
#pragma unroll
            for (int j = 0; j < 4; j++) {
                o[2 * j]     = (bf16_t)(sc * acc[j][0]);
                o[2 * j + 1] = (bf16_t)(sc * acc[j][1]);
            }
            *reinterpret_cast<uint4*>((char*)tout + ((size_t)n << 8) + fl * 16) =
                *reinterpret_cast<const uint4*>(o);
        }
    } else {
        if (g == 0) {
            const int f = fl * 8;
            const float w3 = s3[n], w2 = s2[n], w1 = s1[n];
            float o[8];
#pragma unroll
            for (int j = 0; j < 4; j++) {
                o[2 * j]     = dn * acc[j][0];
                o[2 * j + 1] = dn * acc[j][1];
            }
#pragma unroll
            for (int j = 0; j < 8; j++)
                o[j] += w3 * cvec[f + j] + w2 * cvec[128 + f + j]
                      + w1 * cvec[256 + f + j] + cvec[384 + f + j];
            float* op = fout + (size_t)n * D_OUT + f;
            *reinterpret_cast<float4*>(op)     = make_float4(o[0], o[1], o[2], o[3]);
            *reinterpret_cast<float4*>(op + 4) = make_float4(o[4], o[5], o[6], o[7]);
        }
    }
}

// ---------------- orchestration ----------------
// Algebra (GCN layers are LINEAR — no activation between them):
//   out = Ahat^4 (h0 @ Wbig) + s3 (x) c1 + s2 (x) c2 + s1 (x) c3 + 1 (x) c4
//   Wbig = C1 C2 C3 C4 W2 (512x128), s_k = Ahat^k 1, c_k = bias chains.
// R10: Wbig built RIGHT-associated through the 128-wide dim:
//   T3t = W2^T C4^T = mm3(W2T, C4);  T2t = mm3(T3t, C3);  T1t = mm3(T2t, C2);
//   WbigT = mm3(T1t, C1) -> bf16.    c_r = T_rt . bc_{r-1} (bias_mv, 1 launch).
// Each step M=128 (3x fewer FLOPs than the old 512-wide chain, C_r used
// row-major as given, no extra transposes, vstep chain eliminated).

extern "C" void kernel_launch(void* const* d_in, const int* in_sizes, int n_in,
                              void* d_out, int out_size, void* d_ws, size_t ws_size,
                              hipStream_t stream) {
    const int N = N_NODES, E = N_EDGES;
    const size_t DD = (size_t)D_HID * D_HID;

    const float* x  = (const float*)d_in[0];
    const int*   ei = (const int*)d_in[1];
    const float* W1 = (const float*)d_in[2];
    const float* b1 = (const float*)d_in[3];
    const float* Wc = (const float*)d_in[4];
    const float* bc = (const float*)d_in[5];
    const float* W2 = (const float*)d_in[6];
    const float* b2 = (const float*)d_in[7];
    float* out = (float*)d_out;

    char* ws = (char*)d_ws;
    size_t off = 0;
    auto alloc = [&](size_t bytes) -> void* {
        void* p = ws + off;
        off += (bytes + 255) & ~(size_t)255;
        return p;
    };
    int*    deg       = (int*)alloc((size_t)N * 4);
    int*    cursor    = (int*)alloc((size_t)N * 4);
    int*    row_start = (int*)alloc((size_t)(N + 1) * 4);
    int*    partial   = (int*)alloc(256 * 4);
    float*  dinv      = (float*)alloc((size_t)N_PAD * 4);
    float*  u0        = (float*)alloc((size_t)(N_PAD + 1) * 4);
    float*  u1        = (float*)alloc((size_t)(N_PAD + 1) * 4);
    float*  u2        = (float*)alloc((size_t)(N_PAD + 1) * 4);
    float*  s1        = (float*)alloc((size_t)N * 4);
    float*  s2        = (float*)alloc((size_t)N * 4);
    float*  s3        = (float*)alloc((size_t)N * 4);
    int*    csr_src   = (int*)alloc((size_t)CSR_CAP * 4);
    bf16_t* xb        = (bf16_t*)alloc((size_t)N_PAD * D_IN * 2);
    bf16_t* h0        = (bf16_t*)alloc((size_t)N_PAD * D_HID * 2);
    bf16_t* FA        = (bf16_t*)alloc((size_t)(N_PAD + 1) * D_OUT * 2);  // +1: ZROW
    bf16_t* FB        = (bf16_t*)alloc((size_t)(N_PAD + 1) * D_OUT * 2);  // +1: ZROW
    bf16_t* W1t       = (bf16_t*)alloc((size_t)D_HID * D_IN * 2);
    float*  W2T       = (float*)alloc((size_t)D_OUT * D_HID * 4);
    float*  Tz        = (float*)alloc((size_t)TZ_FLOATS * 4);  // T3t|T2t|T1t (zeroed)
    float*  T3t = Tz, *T2t = Tz + 128 * 512, *T1t = Tz + 2 * 128 * 512;
    bf16_t* WbigT     = (bf16_t*)alloc((size_t)D_OUT * D_HID * 2);
    float*  cvec      = (float*)alloc(4 * 128 * 4);

    // init + x conversion (merged)
    {
        const int nconv = N * D_IN;
        const int nthreads = nconv / 4;          // 3.2M threads (covers all init ranges)
        init_convert<<<(nthreads + 255) / 256, 256, 0, stream>>>(
            deg, cursor, csr_src, dinv, u0, u1, u2, FA, FB, Tz, x, xb, nconv);
    }
    transpose_all<<<dim3(16, 16, 2), dim3(32, 8), 0, stream>>>(W1, W2, W1t, W2T);

    // padded CSR build
    count_deg<<<(E + 255) / 256, 256, 0, stream>>>(ei + E, deg, E);
    const int nch = (N + 1023) / 1024;
    scan_reduce<<<nch, 256, 0, stream>>>(deg, partial, N);
    scan_partials<<<1, 64, 0, stream>>>(partial, nch, row_start, N);
    scan_chunks<<<nch, 1024, 0, stream>>>(deg, partial, row_start, dinv, u0, N);
    fill_csr<<<(E + 255) / 256, 256, 0, stream>>>(ei, E, row_start, cursor, csr_src);

    // T-chain (right-associated, fp32-accurate 3-term split-bf16):
    // T3t = mm3(W2T, C4); T2t = mm3(T3t, C3); T1t = mm3(T2t, C2); WbigT = mm3(T1t, C1)
    mm3<<<dim3(8, 2, 8), 256, 0, stream>>>(
        W2T, Wc + 3 * DD, T3t, nullptr, 128, 512, 512, 8, 0);
    mm3<<<dim3(8, 2, 8), 256, 0, stream>>>(
        T3t, Wc + 2 * DD, T2t, nullptr, 128, 512, 512, 8, 0);
    mm3<<<dim3(8, 2, 8), 256, 0, stream>>>(
        T2t, Wc + 1 * DD, T1t, nullptr, 128, 512, 512, 8, 0);
    mm3<<<dim3(8, 2, 1), 256, 0, stream>>>(
        T1t, Wc, nullptr, WbigT, 128, 512, 512, 1, 1);

    // bias vectors: cvec rows = [bc0.T1, bc1.T2, bc2.T3, bc3.W2 + b2]
    bias_mv<<<2, 256, 0, stream>>>(T1t, T2t, T3t, W2T, bc, b2, cvec);

    // s_k = Ahat^k 1
    s_agg<<<(N + 255) / 256, 256, 0, stream>>>(u0, dinv, row_start, csr_src, s1, u1, N);
    s_agg<<<(N + 255) / 256, 256, 0, stream>>>(u1, dinv, row_start, csr_src, s2, u2, N);
    s_agg<<<(N + 255) / 256, 256, 0, stream>>>(u2, dinv, row_start, csr_src, s3, u1, N);

    const dim3 blk(256);
    const int mg = N_PAD / 128;  // 391

    // dnn1: h0 = relu(x @ W1 + b1)
    gemm_tile<false, true><<<dim3(4, mg), blk, 0, stream>>>(
        xb, W1t, b1, nullptr, h0, N_PAD, D_HID, D_IN);

    // F = dinv .* (h0 @ Wbig)  (prescaled table t0, bf16 128-wide)
    gemm_tile<false, false><<<dim3(1, mg), blk, 0, stream>>>(
        h0, WbigT, nullptr, dinv, FA, N_PAD, D_OUT, D_HID);

    // four hops of Ahat (128-wide); last fuses the rank-4 bias correction + fp32 out
    const int ag = (N + 3) / 4;
    agg128<false><<<ag, blk, 0, stream>>>(FA, dinv, row_start, csr_src, FB, nullptr,
                                          nullptr, nullptr, nullptr, nullptr, N);
    agg128<false><<<ag, blk, 0, stream>>>(FB, dinv, row_start, csr_src, FA, nullptr,
                                          nullptr, nullptr, nullptr, nullptr, N);
    agg128<false><<<ag, blk, 0, stream>>>(FA, dinv, row_start, csr_src, FB, nullptr,
                                          nullptr, nullptr, nullptr, nullptr, N);
    agg128<true><<<ag, blk, 0, stream>>>(FB, dinv, row_start, csr_src, nullptr, out,
                                         s1, s2, s3, cvec, N);
}